// Round 9
// baseline (487.480 us; speedup 1.0000x reference)
//
#include <hip/hip_runtime.h>

// Disable implicit FP contraction: pairwise z^2/e^2 sums must round each
// product individually (numpy semantics). Explicit __fmaf_rn still fuses.
#pragma clang fp contract(off)

// VQ-VAE VectorQuantizer, two-tier:
//  Tier 1: bf16-split MFMA GEMM (zh*eh + zh*el + zl*eh) -> approx scores
//          S_j = ee[j] - 2*dot_j, fused per-row top-2. B (codebook bf16,
//          1 MB) is L2-resident -> loaded DIRECTLY from global, no LDS,
//          no barriers in the K-loop (R8 post-mortem: LDS staging of
//          L2-fit data + 256 barriers was the 28%-MfmaUtil ceiling).
//  Tier 2: rows with top-2 gap <= MARGIN re-scanned with the EXACT np fp32
//          pipeline (R6-proven), batched 16 rows/block.
// Out (f32): [0..16777215] quantized_st, [16777216] loss, [16777217..] idx.
// The q region doubles as scratch for bf16 z (zah/zal) until vq_qwrite.

#define NROWS   65536
#define DDIM    256
#define KCODES  1024
#define QSIZE   (NROWS * DDIM)
#define LOSS_OFF QSIZE
#define IDX_OFF (QSIZE + 1)
#define MARGIN  1.5e-4f
#define RCAP    16384
#define RBATCH  16

typedef __bf16 bf16x8 __attribute__((ext_vector_type(8)));
typedef float f32x4 __attribute__((ext_vector_type(4)));
typedef unsigned int u32;
typedef unsigned long long u64;
typedef unsigned short u16;

__device__ __forceinline__ u32 omap(float s) {
    u32 u = __float_as_uint(s);
    return (u & 0x80000000u) ? ~u : (u | 0x80000000u);
}
__device__ __forceinline__ u64 pack_key(float s, u32 j) {
    return ((u64)omap(s) << 32) | j;
}

// numpy pairwise sum-of-squares over 128 floats (unrolled-8 path)
__device__ __forceinline__ float pw128_sq(const float* __restrict__ x) {
    float r[8];
    #pragma unroll
    for (int j = 0; j < 8; ++j) r[j] = x[j] * x[j];
    for (int i = 8; i < 128; i += 8)
        #pragma unroll
        for (int j = 0; j < 8; ++j) r[j] += x[i + j] * x[i + j];
    return ((r[0] + r[1]) + (r[2] + r[3])) + ((r[4] + r[5]) + (r[6] + r[7]));
}

// ---- codebook prep: ebh/ebl bf16 [ksub(32)][code(1024)][8], np-e2 ----
__global__ __launch_bounds__(256) void vq_pack_cb(
    const float* __restrict__ E, u16* __restrict__ ebh, u16* __restrict__ ebl,
    float* __restrict__ ee, float* __restrict__ sum, int* __restrict__ count) {
    int j = blockIdx.x * 256 + threadIdx.x;
    if (j == 0) { *sum = 0.0f; *count = 0; }
    if (j >= KCODES) return;
    const float* row = E + (size_t)j * DDIM;
    #pragma unroll
    for (int ks = 0; ks < 32; ++ks) {
        bf16x8 h8, l8;
        #pragma unroll
        for (int e = 0; e < 8; ++e) {
            float v = row[ks * 8 + e];
            __bf16 h = (__bf16)v;
            h8[e] = h;
            l8[e] = (__bf16)(v - (float)h);
        }
        *(bf16x8*)(ebh + ((size_t)ks * KCODES + j) * 8) = h8;
        *(bf16x8*)(ebl + ((size_t)ks * KCODES + j) * 8) = l8;
    }
    ee[j] = pw128_sq(row) + pw128_sq(row + 128);
}

// ---- z prep: zah/zal bf16 [ksub(32)][row(65536)][8] into q region; np-z2 ----
__global__ __launch_bounds__(256) void vq_cvt(
    const float* __restrict__ Z, u16* zah, u16* zal, float* __restrict__ z2) {
    __shared__ float zs[32 * 256];
    __shared__ float zacc[32][16];
    const int t = threadIdx.x;
    const size_t rowbase = (size_t)blockIdx.x * 32;
    const float4* Zt = (const float4*)(Z + rowbase * DDIM);
    #pragma unroll
    for (int k = 0; k < 8; ++k) ((float4*)zs)[t + 256 * k] = Zt[t + 256 * k];
    __syncthreads();
    {   // np pairwise z2 (R6-proven ordering)
        int r = t >> 3, j = t & 7;
        const float* zr = zs + r * 256;
        float a0 = zr[j] * zr[j], a1 = zr[128 + j] * zr[128 + j];
        for (int i = 8; i < 128; i += 8) {
            a0 += zr[i + j] * zr[i + j];
            a1 += zr[128 + i + j] * zr[128 + i + j];
        }
        zacc[r][j] = a0; zacc[r][8 + j] = a1;
    }
    __syncthreads();
    if (t < 32) {
        const float* a = zacc[t];
        float c0 = ((a[0] + a[1]) + (a[2] + a[3])) + ((a[4] + a[5]) + (a[6] + a[7]));
        float c1 = ((a[8] + a[9]) + (a[10] + a[11])) + ((a[12] + a[13]) + (a[14] + a[15]));
        z2[rowbase + t] = c0 + c1;
    }
    // bf16 split, k-major pieces: p = t + 256*i -> row=p&31, ksub=p>>5
    #pragma unroll
    for (int i = 0; i < 4; ++i) {
        int p = t + 256 * i;
        int row = p & 31, ks = p >> 5;
        bf16x8 h8, l8;
        #pragma unroll
        for (int e = 0; e < 8; ++e) {
            float v = zs[row * 256 + ks * 8 + e];
            __bf16 h = (__bf16)v;
            h8[e] = h;
            l8[e] = (__bf16)(v - (float)h);
        }
        size_t off = ((size_t)ks * NROWS + rowbase + row) * 8;
        *(bf16x8*)(zah + off) = h8;
        *(bf16x8*)(zal + off) = l8;
    }
}

// ---- tier-1 MFMA GEMM, B direct-from-L2, fused top-2 / flag / loss ----
__global__ __launch_bounds__(256, 2) void vq_gemm(
    const u16* zah, const u16* zal,
    const u16* __restrict__ ebh, const u16* __restrict__ ebl,
    const float* __restrict__ ee, const float* __restrict__ z2,
    float* out, float* __restrict__ sum, int* __restrict__ count,
    int* __restrict__ list) {
    const int t = threadIdx.x, w = t >> 6, l = t & 63;
    const int lr = l & 15, lg = l >> 4;
    const int rowbase = blockIdx.x * 128;

    // A fragments in registers: [rowfrag][kstep], hi/lo
    bf16x8 aH[2][8], aL[2][8];
    #pragma unroll
    for (int rf = 0; rf < 2; ++rf)
        #pragma unroll
        for (int s = 0; s < 8; ++s) {
            size_t off = ((size_t)(s * 4 + lg) * NROWS + rowbase + w * 32 + rf * 16 + lr) * 8;
            aH[rf][s] = *(const bf16x8*)(zah + off);
            aL[rf][s] = *(const bf16x8*)(zal + off);
        }

    u64 k1[2][4]; float s1[2][4], s2[2][4];
    #pragma unroll
    for (int rf = 0; rf < 2; ++rf)
        #pragma unroll
        for (int r = 0; r < 4; ++r) { k1[rf][r] = ~0ULL; s1[rf][r] = 1e30f; s2[rf][r] = 1e30f; }

    for (int ch = 0; ch < 16; ++ch) {
        const int chbase = ch * 64;
        f32x4 acc[2][4];
        #pragma unroll
        for (int rf = 0; rf < 2; ++rf)
            #pragma unroll
            for (int cf = 0; cf < 4; ++cf) acc[rf][cf] = 0.0f;

        #pragma unroll
        for (int s = 0; s < 8; ++s) {
            #pragma unroll
            for (int cf = 0; cf < 4; ++cf) {
                size_t boff = ((size_t)(s * 4 + lg) * KCODES + chbase + cf * 16 + lr) * 8;
                bf16x8 bh = *(const bf16x8*)(ebh + boff);   // L2-hit, coalesced
                bf16x8 bl = *(const bf16x8*)(ebl + boff);
                #pragma unroll
                for (int rf = 0; rf < 2; ++rf) {
                    acc[rf][cf] = __builtin_amdgcn_mfma_f32_16x16x32_bf16(aH[rf][s], bh, acc[rf][cf], 0, 0, 0);
                    acc[rf][cf] = __builtin_amdgcn_mfma_f32_16x16x32_bf16(aH[rf][s], bl, acc[rf][cf], 0, 0, 0);
                    acc[rf][cf] = __builtin_amdgcn_mfma_f32_16x16x32_bf16(aL[rf][s], bh, acc[rf][cf], 0, 0, 0);
                }
            }
        }
        // chunk epilogue: per-lane running top-2 over its 4 codes
        #pragma unroll
        for (int cf = 0; cf < 4; ++cf) {
            int code = chbase + cf * 16 + lr;
            float e2c = ee[code];
            #pragma unroll
            for (int rf = 0; rf < 2; ++rf)
                #pragma unroll
                for (int r = 0; r < 4; ++r) {
                    float v = e2c - 2.0f * acc[rf][cf][r];
                    u64 k = pack_key(v, (u32)code);
                    if (k < k1[rf][r]) { s2[rf][r] = fminf(s2[rf][r], s1[rf][r]); s1[rf][r] = v; k1[rf][r] = k; }
                    else               { s2[rf][r] = fminf(s2[rf][r], v); }
                }
        }
    }
    // butterfly across the 16 lanes of each row group (lr bits only)
    #pragma unroll
    for (int off = 1; off < 16; off <<= 1) {
        #pragma unroll
        for (int rf = 0; rf < 2; ++rf)
            #pragma unroll
            for (int r = 0; r < 4; ++r) {
                u64 ok = __shfl_xor(k1[rf][r], off);
                float os1 = __shfl_xor(s1[rf][r], off);
                float os2 = __shfl_xor(s2[rf][r], off);
                bool other = ok < k1[rf][r];
                float worse = other ? s1[rf][r] : os1;
                if (other) { k1[rf][r] = ok; s1[rf][r] = os1; }
                s2[rf][r] = fminf(fminf(s2[rf][r], os2), worse);
            }
    }
    if (lr == 0) {
        float lsum = 0.0f;
        #pragma unroll
        for (int rf = 0; rf < 2; ++rf)
            #pragma unroll
            for (int r = 0; r < 4; ++r) {
                int row = rowbase + w * 32 + rf * 16 + lg * 4 + r;
                int code = (int)(k1[rf][r] & 1023ULL);
                out[(size_t)IDX_OFF + row] = (float)code;
                lsum += z2[row] + s1[rf][r];
                if (s2[rf][r] <= s1[rf][r] + MARGIN) {
                    int slot = atomicAdd(count, 1);
                    if (slot < RCAP) list[slot] = row;
                }
            }
        atomicAdd(sum, lsum);
    }
}

// ---- tier-2 exact np re-scan, BATCHED 16 rows/block (R6 arithmetic) ----
__global__ __launch_bounds__(256) void vq_rescue(
    const float* __restrict__ Z, const float* __restrict__ E,
    const float* __restrict__ ee, const int* __restrict__ count,
    const int* __restrict__ list, float* out) {
    __shared__ float zrow[RBATCH][DDIM];    // 16 KB
    __shared__ float zacc[RBATCH][16];
    __shared__ float z2s[RBATCH];
    __shared__ u64 rmin[RBATCH];
    __shared__ int rowid[RBATCH];
    int n = *count; if (n > RCAP) n = RCAP;
    const int t = threadIdx.x;
    const int base = blockIdx.x * RBATCH;
    if (base >= n) return;
    int nb = n - base; if (nb > RBATCH) nb = RBATCH;

    if (t < RBATCH) {
        rowid[t] = (t < nb) ? list[base + t] : 0;
        rmin[t] = ~0ULL;
    }
    __syncthreads();
    // stage z rows (coalesced float4): 16 rows x 64 float4
    #pragma unroll
    for (int i = 0; i < RBATCH * (DDIM / 4) / 256; ++i) {
        int p = t + 256 * i;
        int r = p >> 6, c4 = p & 63;
        if (r < nb) ((float4*)zrow[r])[c4] =
            ((const float4*)(Z + (size_t)rowid[r] * DDIM))[c4];
    }
    __syncthreads();
    // np pairwise z2 per row
    if (t < RBATCH * 8) {
        int r = t >> 3, j = t & 7;
        const float* zr = zrow[r];
        float a0 = zr[j] * zr[j], a1 = zr[128 + j] * zr[128 + j];
        for (int i = 8; i < 128; i += 8) {
            a0 += zr[i + j] * zr[i + j];
            a1 += zr[128 + i + j] * zr[128 + i + j];
        }
        zacc[r][j] = a0; zacc[r][8 + j] = a1;
    }
    __syncthreads();
    if (t < RBATCH) {
        const float* a = zacc[t];
        float c0 = ((a[0] + a[1]) + (a[2] + a[3])) + ((a[4] + a[5]) + (a[6] + a[7]));
        float c1 = ((a[8] + a[9]) + (a[10] + a[11])) + ((a[12] + a[13]) + (a[14] + a[15]));
        z2s[t] = c0 + c1;
    }
    __syncthreads();

    // dots: thread t owns codes {t,+256,+512,+768} x all RBATCH rows;
    // strict sequential fp32 FMA chain over k ascending per (row,code).
    float acc[4][RBATCH];
    #pragma unroll
    for (int c = 0; c < 4; ++c)
        #pragma unroll
        for (int r = 0; r < RBATCH; ++r) acc[c][r] = 0.0f;

    for (int d4 = 0; d4 < DDIM / 4; ++d4) {
        float4 ev[4];
        #pragma unroll
        for (int c = 0; c < 4; ++c)
            ev[c] = ((const float4*)(E + (size_t)(t + c * 256) * DDIM))[d4];
        #pragma unroll
        for (int r = 0; r < RBATCH; ++r) {
            float4 zv = ((const float4*)zrow[r])[d4];
            #pragma unroll
            for (int c = 0; c < 4; ++c) {
                float a = acc[c][r];
                a = __fmaf_rn(zv.x, ev[c].x, a); a = __fmaf_rn(zv.y, ev[c].y, a);
                a = __fmaf_rn(zv.z, ev[c].z, a); a = __fmaf_rn(zv.w, ev[c].w, a);
                acc[c][r] = a;
            }
        }
    }
    // per-row argmin: np full-magnitude combine + first-min tie-break
    float e2c[4];
    #pragma unroll
    for (int c = 0; c < 4; ++c) e2c[c] = ee[t + c * 256];
    #pragma unroll
    for (int r = 0; r < RBATCH; ++r) {
        float zr2 = z2s[r];
        u64 best = ~0ULL;
        #pragma unroll
        for (int c = 0; c < 4; ++c) {
            float d = (zr2 + e2c[c]) - 2.0f * acc[c][r];
            u64 k = pack_key(d, (u32)(t + c * 256));
            if (k < best) best = k;
        }
        #pragma unroll
        for (int off = 1; off < 64; off <<= 1) {
            u64 o = __shfl_xor(best, off);
            if (o < best) best = o;
        }
        if ((t & 63) == 0) atomicMin(&rmin[r], best);
    }
    __syncthreads();
    if (t < nb) out[(size_t)IDX_OFF + rowid[t]] = (float)(u32)(rmin[t] & 0xFFFFFFFFu);
}

// ---- gather codebook rows into quantized output (overwrites scratch) ----
__global__ __launch_bounds__(256) void vq_qwrite(const float* __restrict__ E, float* out) {
    __shared__ int qidx[32];
    const int t = threadIdx.x;
    const size_t rowbase = (size_t)blockIdx.x * 32;
    if (t < 32) qidx[t] = (int)out[(size_t)IDX_OFF + rowbase + t];
    __syncthreads();
    float4* outq = (float4*)out;
    #pragma unroll
    for (int k = 0; k < 8; ++k) {
        int idx = t + 256 * k;
        int r = idx >> 6, c4 = idx & 63;
        int code = qidx[r];
        outq[rowbase * 64 + idx] = ((const float4*)(E + (size_t)code * DDIM))[c4];
    }
}

__global__ void vq_finalize(const float* __restrict__ sum, float* __restrict__ out) {
    out[LOSS_OFF] = 1.25f * (*sum) / (float)QSIZE;
}

extern "C" void kernel_launch(void* const* d_in, const int* in_sizes, int n_in,
                              void* d_out, int out_size, void* d_ws, size_t ws_size,
                              hipStream_t stream) {
    const float* Z; const float* E;
    if (in_sizes[0] == QSIZE) { Z = (const float*)d_in[0]; E = (const float*)d_in[1]; }
    else                      { Z = (const float*)d_in[1]; E = (const float*)d_in[0]; }
    float* out = (float*)d_out;
    char* ws = (char*)d_ws;

    float* sum  = (float*)ws;                       // @0
    int*   count = (int*)(ws + 4);                  // @4
    float* ee   = (float*)(ws + 1024);              // 4 KB
    float* z2   = (float*)(ws + 8192);              // 256 KB
    u16*   ebh  = (u16*)(ws + 270336);              // 512 KB
    u16*   ebl  = (u16*)(ws + 270336 + 524288);     // 512 KB
    int*   list = (int*)(ws + 270336 + 1048576);    // 64 KB  (total ~1.38 MB)

    // bf16 z scratch lives in the q-output region until vq_qwrite
    u16* zah = (u16*)out;
    u16* zal = (u16*)out + (size_t)QSIZE;           // ushort offset = QSIZE

    vq_pack_cb<<<4, 256, 0, stream>>>(E, ebh, ebl, ee, sum, count);
    vq_cvt<<<NROWS / 32, 256, 0, stream>>>(Z, zah, zal, z2);
    vq_gemm<<<NROWS / 128, 256, 0, stream>>>(zah, zal, ebh, ebl, ee, z2, out, sum, count, list);
    vq_rescue<<<RCAP / RBATCH, 256, 0, stream>>>(Z, E, ee, count, list, out);
    vq_qwrite<<<NROWS / 32, 256, 0, stream>>>(E, out);
    vq_finalize<<<1, 1, 0, stream>>>(sum, out);
}

// Round 10
// 262.576 us; speedup vs baseline: 1.8565x; 1.8565x over previous
//
#include <hip/hip_runtime.h>

// Disable implicit FP contraction: pairwise z^2/e^2 sums must round each
// product individually (numpy semantics). Explicit __fmaf_rn still fuses.
#pragma clang fp contract(off)

// VQ-VAE VectorQuantizer, two-tier:
//  Tier 1: bf16-split MFMA GEMM (zh*eh + zh*el + zl*eh) -> approx scores,
//          fused per-row top-2. B staged to LDS via global_load_lds (w=16),
//          double-buffered 32-code chunks, ONE barrier per chunk (32 total
//          vs R8's 256), next-chunk loads issued under current-chunk MFMA.
//          (R9 lesson: direct-L2 B thrashes -> 363 MB HBM refetch; staging
//           gives B its reuse. R8 lesson: per-kstep barriers cap MfmaUtil.)
//  Tier 2: rows with top-2 gap <= MARGIN re-scanned with the EXACT np fp32
//          pipeline (R6-proven), batched 16 rows/block.
// Out (f32): [0..16777215] quantized_st, [16777216] loss, [16777217..] idx.
// The q region doubles as scratch for bf16 z (zah/zal) until vq_qwrite.

#define NROWS   65536
#define DDIM    256
#define KCODES  1024
#define QSIZE   (NROWS * DDIM)
#define LOSS_OFF QSIZE
#define IDX_OFF (QSIZE + 1)
#define MARGIN  1.5e-4f
#define RCAP    16384
#define RBATCH  16

typedef __bf16 bf16x8 __attribute__((ext_vector_type(8)));
typedef float f32x4 __attribute__((ext_vector_type(4)));
typedef unsigned int u32;
typedef unsigned long long u64;
typedef unsigned short u16;

#define GLOAD_LDS16(gsrc, ldst) \
    __builtin_amdgcn_global_load_lds( \
        (const __attribute__((address_space(1))) u32*)(gsrc), \
        (__attribute__((address_space(3))) u32*)(ldst), 16, 0, 0)

__device__ __forceinline__ u32 omap(float s) {
    u32 u = __float_as_uint(s);
    return (u & 0x80000000u) ? ~u : (u | 0x80000000u);
}
__device__ __forceinline__ u64 pack_key(float s, u32 j) {
    return ((u64)omap(s) << 32) | j;
}

// numpy pairwise sum-of-squares over 128 floats (unrolled-8 path)
__device__ __forceinline__ float pw128_sq(const float* __restrict__ x) {
    float r[8];
    #pragma unroll
    for (int j = 0; j < 8; ++j) r[j] = x[j] * x[j];
    for (int i = 8; i < 128; i += 8)
        #pragma unroll
        for (int j = 0; j < 8; ++j) r[j] += x[i + j] * x[i + j];
    return ((r[0] + r[1]) + (r[2] + r[3])) + ((r[4] + r[5]) + (r[6] + r[7]));
}

// ---- codebook prep: ebh/ebl bf16 [ksub(32)][code(1024)][8], np-e2 ----
__global__ __launch_bounds__(256) void vq_pack_cb(
    const float* __restrict__ E, u16* __restrict__ ebh, u16* __restrict__ ebl,
    float* __restrict__ ee, float* __restrict__ sum, int* __restrict__ count) {
    int j = blockIdx.x * 256 + threadIdx.x;
    if (j == 0) { *sum = 0.0f; *count = 0; }
    if (j >= KCODES) return;
    const float* row = E + (size_t)j * DDIM;
    #pragma unroll
    for (int ks = 0; ks < 32; ++ks) {
        bf16x8 h8, l8;
        #pragma unroll
        for (int e = 0; e < 8; ++e) {
            float v = row[ks * 8 + e];
            __bf16 h = (__bf16)v;
            h8[e] = h;
            l8[e] = (__bf16)(v - (float)h);
        }
        *(bf16x8*)(ebh + ((size_t)ks * KCODES + j) * 8) = h8;
        *(bf16x8*)(ebl + ((size_t)ks * KCODES + j) * 8) = l8;
    }
    ee[j] = pw128_sq(row) + pw128_sq(row + 128);
}

// ---- z prep: zah/zal bf16 [ksub(32)][row(65536)][8] into q region; np-z2 ----
__global__ __launch_bounds__(256) void vq_cvt(
    const float* __restrict__ Z, u16* zah, u16* zal, float* __restrict__ z2) {
    __shared__ float zs[32 * 256];
    __shared__ float zacc[32][16];
    const int t = threadIdx.x;
    const size_t rowbase = (size_t)blockIdx.x * 32;
    const float4* Zt = (const float4*)(Z + rowbase * DDIM);
    #pragma unroll
    for (int k = 0; k < 8; ++k) ((float4*)zs)[t + 256 * k] = Zt[t + 256 * k];
    __syncthreads();
    {   // np pairwise z2 (R6-proven ordering)
        int r = t >> 3, j = t & 7;
        const float* zr = zs + r * 256;
        float a0 = zr[j] * zr[j], a1 = zr[128 + j] * zr[128 + j];
        for (int i = 8; i < 128; i += 8) {
            a0 += zr[i + j] * zr[i + j];
            a1 += zr[128 + i + j] * zr[128 + i + j];
        }
        zacc[r][j] = a0; zacc[r][8 + j] = a1;
    }
    __syncthreads();
    if (t < 32) {
        const float* a = zacc[t];
        float c0 = ((a[0] + a[1]) + (a[2] + a[3])) + ((a[4] + a[5]) + (a[6] + a[7]));
        float c1 = ((a[8] + a[9]) + (a[10] + a[11])) + ((a[12] + a[13]) + (a[14] + a[15]));
        z2[rowbase + t] = c0 + c1;
    }
    // bf16 split, k-major pieces: p = t + 256*i -> row=p&31, ksub=p>>5
    #pragma unroll
    for (int i = 0; i < 4; ++i) {
        int p = t + 256 * i;
        int row = p & 31, ks = p >> 5;
        bf16x8 h8, l8;
        #pragma unroll
        for (int e = 0; e < 8; ++e) {
            float v = zs[row * 256 + ks * 8 + e];
            __bf16 h = (__bf16)v;
            h8[e] = h;
            l8[e] = (__bf16)(v - (float)h);
        }
        size_t off = ((size_t)ks * NROWS + rowbase + row) * 8;
        *(bf16x8*)(zah + off) = h8;
        *(bf16x8*)(zal + off) = l8;
    }
}

// ---- tier-1 MFMA GEMM: LDS-staged B (dbuf, 1 barrier/chunk), top-2 fused ----
__device__ __forceinline__ void stage_chunk(
    const u16* __restrict__ ebh, const u16* __restrict__ ebl,
    int chbase, char* buf, int t) {
    // 32 codes x 32 ksubs x 16B, hi then lo; lane-linear LDS (p*16)
    #pragma unroll
    for (int i = 0; i < 4; ++i) {
        int p = t + 256 * i;
        int ks = p >> 5, c = p & 31;
        GLOAD_LDS16(ebh + ((size_t)ks * KCODES + chbase + c) * 8, buf + p * 16);
    }
    #pragma unroll
    for (int i = 0; i < 4; ++i) {
        int p = t + 256 * i;
        int ks = p >> 5, c = p & 31;
        GLOAD_LDS16(ebl + ((size_t)ks * KCODES + chbase + c) * 8, buf + 16384 + p * 16);
    }
}

__global__ __launch_bounds__(256, 2) void vq_gemm(
    const u16* zah, const u16* zal,
    const u16* __restrict__ ebh, const u16* __restrict__ ebl,
    const float* __restrict__ ee, const float* __restrict__ z2,
    float* out, float* __restrict__ sum, int* __restrict__ count,
    int* __restrict__ list) {
    __shared__ __align__(16) char bs[2][32768];   // double-buffered B chunk
    const int t = threadIdx.x, w = t >> 6, l = t & 63;
    const int lr = l & 15, lg = l >> 4;
    const int rowbase = blockIdx.x * 128;

    // A fragments in registers: [rowfrag][kstep], hi/lo
    bf16x8 aH[2][8], aL[2][8];
    #pragma unroll
    for (int rf = 0; rf < 2; ++rf)
        #pragma unroll
        for (int s = 0; s < 8; ++s) {
            size_t off = ((size_t)(s * 4 + lg) * NROWS + rowbase + w * 32 + rf * 16 + lr) * 8;
            aH[rf][s] = *(const bf16x8*)(zah + off);
            aL[rf][s] = *(const bf16x8*)(zal + off);
        }

    u64 k1[2][4]; float s1[2][4], s2[2][4];
    #pragma unroll
    for (int rf = 0; rf < 2; ++rf)
        #pragma unroll
        for (int r = 0; r < 4; ++r) { k1[rf][r] = ~0ULL; s1[rf][r] = 1e30f; s2[rf][r] = 1e30f; }

    int cur = 0;
    stage_chunk(ebh, ebl, 0, bs[0], t);
    for (int ch = 0; ch < 32; ++ch) {
        __syncthreads();                    // drains this chunk's gload_lds
        if (ch + 1 < 32) stage_chunk(ebh, ebl, (ch + 1) * 32, bs[cur ^ 1], t);
        const char* buf = bs[cur];
        const int chbase = ch * 32;

        f32x4 acc[2][2];
        #pragma unroll
        for (int rf = 0; rf < 2; ++rf)
            #pragma unroll
            for (int cf = 0; cf < 2; ++cf) acc[rf][cf] = 0.0f;

        #pragma unroll
        for (int s = 0; s < 8; ++s) {
            #pragma unroll
            for (int cf = 0; cf < 2; ++cf) {
                int off = (((s * 4 + lg) * 32 + cf * 16 + lr) * 16);
                bf16x8 bh = *(const bf16x8*)(buf + off);
                bf16x8 bl = *(const bf16x8*)(buf + 16384 + off);
                #pragma unroll
                for (int rf = 0; rf < 2; ++rf) {
                    acc[rf][cf] = __builtin_amdgcn_mfma_f32_16x16x32_bf16(aH[rf][s], bh, acc[rf][cf], 0, 0, 0);
                    acc[rf][cf] = __builtin_amdgcn_mfma_f32_16x16x32_bf16(aH[rf][s], bl, acc[rf][cf], 0, 0, 0);
                    acc[rf][cf] = __builtin_amdgcn_mfma_f32_16x16x32_bf16(aL[rf][s], bh, acc[rf][cf], 0, 0, 0);
                }
            }
        }
        // chunk epilogue: per-lane running top-2 over its 2 codes
        #pragma unroll
        for (int cf = 0; cf < 2; ++cf) {
            int code = chbase + cf * 16 + lr;
            float e2c = ee[code];
            #pragma unroll
            for (int rf = 0; rf < 2; ++rf)
                #pragma unroll
                for (int r = 0; r < 4; ++r) {
                    float v = e2c - 2.0f * acc[rf][cf][r];
                    u64 k = pack_key(v, (u32)code);
                    if (k < k1[rf][r]) { s2[rf][r] = fminf(s2[rf][r], s1[rf][r]); s1[rf][r] = v; k1[rf][r] = k; }
                    else               { s2[rf][r] = fminf(s2[rf][r], v); }
                }
        }
        cur ^= 1;
    }
    // butterfly across the 16 lanes of each row group (lr bits only)
    #pragma unroll
    for (int off = 1; off < 16; off <<= 1) {
        #pragma unroll
        for (int rf = 0; rf < 2; ++rf)
            #pragma unroll
            for (int r = 0; r < 4; ++r) {
                u64 ok = __shfl_xor(k1[rf][r], off);
                float os1 = __shfl_xor(s1[rf][r], off);
                float os2 = __shfl_xor(s2[rf][r], off);
                bool other = ok < k1[rf][r];
                float worse = other ? s1[rf][r] : os1;
                if (other) { k1[rf][r] = ok; s1[rf][r] = os1; }
                s2[rf][r] = fminf(fminf(s2[rf][r], os2), worse);
            }
    }
    if (lr == 0) {
        float lsum = 0.0f;
        #pragma unroll
        for (int rf = 0; rf < 2; ++rf)
            #pragma unroll
            for (int r = 0; r < 4; ++r) {
                int row = rowbase + w * 32 + rf * 16 + lg * 4 + r;
                int code = (int)(k1[rf][r] & 1023ULL);
                out[(size_t)IDX_OFF + row] = (float)code;
                lsum += z2[row] + s1[rf][r];
                if (s2[rf][r] <= s1[rf][r] + MARGIN) {
                    int slot = atomicAdd(count, 1);
                    if (slot < RCAP) list[slot] = row;
                }
            }
        atomicAdd(sum, lsum);
    }
}

// ---- tier-2 exact np re-scan, BATCHED 16 rows/block (R6 arithmetic) ----
__global__ __launch_bounds__(256) void vq_rescue(
    const float* __restrict__ Z, const float* __restrict__ E,
    const float* __restrict__ ee, const int* __restrict__ count,
    const int* __restrict__ list, float* out) {
    __shared__ float zrow[RBATCH][DDIM];    // 16 KB
    __shared__ float zacc[RBATCH][16];
    __shared__ float z2s[RBATCH];
    __shared__ u64 rmin[RBATCH];
    __shared__ int rowid[RBATCH];
    int n = *count; if (n > RCAP) n = RCAP;
    const int t = threadIdx.x;
    const int base = blockIdx.x * RBATCH;
    if (base >= n) return;
    int nb = n - base; if (nb > RBATCH) nb = RBATCH;

    if (t < RBATCH) {
        rowid[t] = (t < nb) ? list[base + t] : 0;
        rmin[t] = ~0ULL;
    }
    __syncthreads();
    // stage z rows (coalesced float4): 16 rows x 64 float4
    #pragma unroll
    for (int i = 0; i < RBATCH * (DDIM / 4) / 256; ++i) {
        int p = t + 256 * i;
        int r = p >> 6, c4 = p & 63;
        if (r < nb) ((float4*)zrow[r])[c4] =
            ((const float4*)(Z + (size_t)rowid[r] * DDIM))[c4];
    }
    __syncthreads();
    // np pairwise z2 per row
    if (t < RBATCH * 8) {
        int r = t >> 3, j = t & 7;
        const float* zr = zrow[r];
        float a0 = zr[j] * zr[j], a1 = zr[128 + j] * zr[128 + j];
        for (int i = 8; i < 128; i += 8) {
            a0 += zr[i + j] * zr[i + j];
            a1 += zr[128 + i + j] * zr[128 + i + j];
        }
        zacc[r][j] = a0; zacc[r][8 + j] = a1;
    }
    __syncthreads();
    if (t < RBATCH) {
        const float* a = zacc[t];
        float c0 = ((a[0] + a[1]) + (a[2] + a[3])) + ((a[4] + a[5]) + (a[6] + a[7]));
        float c1 = ((a[8] + a[9]) + (a[10] + a[11])) + ((a[12] + a[13]) + (a[14] + a[15]));
        z2s[t] = c0 + c1;
    }
    __syncthreads();

    // dots: thread t owns codes {t,+256,+512,+768} x all RBATCH rows;
    // strict sequential fp32 FMA chain over k ascending per (row,code).
    float acc[4][RBATCH];
    #pragma unroll
    for (int c = 0; c < 4; ++c)
        #pragma unroll
        for (int r = 0; r < RBATCH; ++r) acc[c][r] = 0.0f;

    for (int d4 = 0; d4 < DDIM / 4; ++d4) {
        float4 ev[4];
        #pragma unroll
        for (int c = 0; c < 4; ++c)
            ev[c] = ((const float4*)(E + (size_t)(t + c * 256) * DDIM))[d4];
        #pragma unroll
        for (int r = 0; r < RBATCH; ++r) {
            float4 zv = ((const float4*)zrow[r])[d4];
            #pragma unroll
            for (int c = 0; c < 4; ++c) {
                float a = acc[c][r];
                a = __fmaf_rn(zv.x, ev[c].x, a); a = __fmaf_rn(zv.y, ev[c].y, a);
                a = __fmaf_rn(zv.z, ev[c].z, a); a = __fmaf_rn(zv.w, ev[c].w, a);
                acc[c][r] = a;
            }
        }
    }
    // per-row argmin: np full-magnitude combine + first-min tie-break
    float e2c[4];
    #pragma unroll
    for (int c = 0; c < 4; ++c) e2c[c] = ee[t + c * 256];
    #pragma unroll
    for (int r = 0; r < RBATCH; ++r) {
        float zr2 = z2s[r];
        u64 best = ~0ULL;
        #pragma unroll
        for (int c = 0; c < 4; ++c) {
            float d = (zr2 + e2c[c]) - 2.0f * acc[c][r];
            u64 k = pack_key(d, (u32)(t + c * 256));
            if (k < best) best = k;
        }
        #pragma unroll
        for (int off = 1; off < 64; off <<= 1) {
            u64 o = __shfl_xor(best, off);
            if (o < best) best = o;
        }
        if ((t & 63) == 0) atomicMin(&rmin[r], best);
    }
    __syncthreads();
    if (t < nb) out[(size_t)IDX_OFF + rowid[t]] = (float)(u32)(rmin[t] & 0xFFFFFFFFu);
}

// ---- gather codebook rows into quantized output (overwrites scratch) ----
__global__ __launch_bounds__(256) void vq_qwrite(const float* __restrict__ E, float* out) {
    __shared__ int qidx[32];
    const int t = threadIdx.x;
    const size_t rowbase = (size_t)blockIdx.x * 32;
    if (t < 32) qidx[t] = (int)out[(size_t)IDX_OFF + rowbase + t];
    __syncthreads();
    float4* outq = (float4*)out;
    #pragma unroll
    for (int k = 0; k < 8; ++k) {
        int idx = t + 256 * k;
        int r = idx >> 6, c4 = idx & 63;
        int code = qidx[r];
        outq[rowbase * 64 + idx] = ((const float4*)(E + (size_t)code * DDIM))[c4];
    }
}

__global__ void vq_finalize(const float* __restrict__ sum, float* __restrict__ out) {
    out[LOSS_OFF] = 1.25f * (*sum) / (float)QSIZE;
}

extern "C" void kernel_launch(void* const* d_in, const int* in_sizes, int n_in,
                              void* d_out, int out_size, void* d_ws, size_t ws_size,
                              hipStream_t stream) {
    const float* Z; const float* E;
    if (in_sizes[0] == QSIZE) { Z = (const float*)d_in[0]; E = (const float*)d_in[1]; }
    else                      { Z = (const float*)d_in[1]; E = (const float*)d_in[0]; }
    float* out = (float*)d_out;
    char* ws = (char*)d_ws;

    float* sum  = (float*)ws;                       // @0
    int*   count = (int*)(ws + 4);                  // @4
    float* ee   = (float*)(ws + 1024);              // 4 KB
    float* z2   = (float*)(ws + 8192);              // 256 KB
    u16*   ebh  = (u16*)(ws + 270336);              // 512 KB
    u16*   ebl  = (u16*)(ws + 270336 + 524288);     // 512 KB
    int*   list = (int*)(ws + 270336 + 1048576);    // 64 KB  (total ~1.38 MB)

    // bf16 z scratch lives in the q-output region until vq_qwrite
    u16* zah = (u16*)out;
    u16* zal = (u16*)out + (size_t)QSIZE;           // ushort offset = QSIZE

    vq_pack_cb<<<4, 256, 0, stream>>>(E, ebh, ebl, ee, sum, count);
    vq_cvt<<<NROWS / 32, 256, 0, stream>>>(Z, zah, zal, z2);
    vq_gemm<<<NROWS / 128, 256, 0, stream>>>(zah, zal, ebh, ebl, ee, z2, out, sum, count, list);
    vq_rescue<<<RCAP / RBATCH, 256, 0, stream>>>(Z, E, ee, count, list, out);
    vq_qwrite<<<NROWS / 32, 256, 0, stream>>>(E, out);
    vq_finalize<<<1, 1, 0, stream>>>(sum, out);
}

// Round 11
// 259.482 us; speedup vs baseline: 1.8787x; 1.0119x over previous
//
#include <hip/hip_runtime.h>

// Disable implicit FP contraction: pairwise z^2/e^2 sums must round each
// product individually (numpy semantics). Explicit __fmaf_rn still fuses.
#pragma clang fp contract(off)

// VQ-VAE VectorQuantizer, two-tier:
//  Tier 1: plain-bf16 MFMA GEMM (zh*eh only) -> approx scores, error rms
//          ~3e-5 (same order as np's own fp32 quantization). Fused top-2;
//          rows with approx top-2 gap <= MARGIN=3e-4 (~8 sigma) flagged.
//          B staged to LDS via global_load_lds, double-buffered 32-code
//          chunks, one barrier per chunk (R9: direct-L2 B thrashes HBM;
//          R8: per-kstep barriers; R10 post-mortem: 3-product split was
//          numeric overkill -> 3x MFMA + 2x LDS traffic for nothing).
//  Tier 2: flagged rows re-scanned with the EXACT np fp32 pipeline
//          (R6-proven), batched 16 rows/block -> tier-1 precision never
//          affects final indices of flagged rows.
// Out (f32): [0..16777215] quantized_st, [16777216] loss, [16777217..] idx.
// The q region doubles as scratch for bf16 z (zah) until vq_qwrite.

#define NROWS   65536
#define DDIM    256
#define KCODES  1024
#define QSIZE   (NROWS * DDIM)
#define LOSS_OFF QSIZE
#define IDX_OFF (QSIZE + 1)
#define MARGIN  3.0e-4f
#define RCAP    16384
#define RBATCH  16

typedef __bf16 bf16x8 __attribute__((ext_vector_type(8)));
typedef float f32x4 __attribute__((ext_vector_type(4)));
typedef unsigned int u32;
typedef unsigned long long u64;
typedef unsigned short u16;

#define GLOAD_LDS16(gsrc, ldst) \
    __builtin_amdgcn_global_load_lds( \
        (const __attribute__((address_space(1))) u32*)(gsrc), \
        (__attribute__((address_space(3))) u32*)(ldst), 16, 0, 0)

__device__ __forceinline__ u32 omap(float s) {
    u32 u = __float_as_uint(s);
    return (u & 0x80000000u) ? ~u : (u | 0x80000000u);
}
__device__ __forceinline__ u64 pack_key(float s, u32 j) {
    return ((u64)omap(s) << 32) | j;
}

// numpy pairwise sum-of-squares over 128 floats (unrolled-8 path)
__device__ __forceinline__ float pw128_sq(const float* __restrict__ x) {
    float r[8];
    #pragma unroll
    for (int j = 0; j < 8; ++j) r[j] = x[j] * x[j];
    for (int i = 8; i < 128; i += 8)
        #pragma unroll
        for (int j = 0; j < 8; ++j) r[j] += x[i + j] * x[i + j];
    return ((r[0] + r[1]) + (r[2] + r[3])) + ((r[4] + r[5]) + (r[6] + r[7]));
}

// ---- codebook prep: ebh bf16 [ksub(32)][code(1024)][8], np-e2 ----
__global__ __launch_bounds__(256) void vq_pack_cb(
    const float* __restrict__ E, u16* __restrict__ ebh,
    float* __restrict__ ee, float* __restrict__ sum, int* __restrict__ count) {
    int j = blockIdx.x * 256 + threadIdx.x;
    if (j == 0) { *sum = 0.0f; *count = 0; }
    if (j >= KCODES) return;
    const float* row = E + (size_t)j * DDIM;
    #pragma unroll
    for (int ks = 0; ks < 32; ++ks) {
        bf16x8 h8;
        #pragma unroll
        for (int e = 0; e < 8; ++e) h8[e] = (__bf16)row[ks * 8 + e];
        *(bf16x8*)(ebh + ((size_t)ks * KCODES + j) * 8) = h8;
    }
    ee[j] = pw128_sq(row) + pw128_sq(row + 128);
}

// ---- z prep: zah bf16 [ksub(32)][row(65536)][8] into q region; np-z2 ----
__global__ __launch_bounds__(256) void vq_cvt(
    const float* __restrict__ Z, u16* zah, float* __restrict__ z2) {
    __shared__ float zs[32 * 256];
    __shared__ float zacc[32][16];
    const int t = threadIdx.x;
    const size_t rowbase = (size_t)blockIdx.x * 32;
    const float4* Zt = (const float4*)(Z + rowbase * DDIM);
    #pragma unroll
    for (int k = 0; k < 8; ++k) ((float4*)zs)[t + 256 * k] = Zt[t + 256 * k];
    __syncthreads();
    {   // np pairwise z2 (R6-proven ordering)
        int r = t >> 3, j = t & 7;
        const float* zr = zs + r * 256;
        float a0 = zr[j] * zr[j], a1 = zr[128 + j] * zr[128 + j];
        for (int i = 8; i < 128; i += 8) {
            a0 += zr[i + j] * zr[i + j];
            a1 += zr[128 + i + j] * zr[128 + i + j];
        }
        zacc[r][j] = a0; zacc[r][8 + j] = a1;
    }
    __syncthreads();
    if (t < 32) {
        const float* a = zacc[t];
        float c0 = ((a[0] + a[1]) + (a[2] + a[3])) + ((a[4] + a[5]) + (a[6] + a[7]));
        float c1 = ((a[8] + a[9]) + (a[10] + a[11])) + ((a[12] + a[13]) + (a[14] + a[15]));
        z2[rowbase + t] = c0 + c1;
    }
    // bf16 convert, k-major pieces: p = t + 256*i -> row=p&31, ksub=p>>5
    #pragma unroll
    for (int i = 0; i < 4; ++i) {
        int p = t + 256 * i;
        int row = p & 31, ks = p >> 5;
        bf16x8 h8;
        #pragma unroll
        for (int e = 0; e < 8; ++e) h8[e] = (__bf16)zs[row * 256 + ks * 8 + e];
        *(bf16x8*)(zah + ((size_t)ks * NROWS + rowbase + row) * 8) = h8;
    }
}

// ---- tier-1 MFMA GEMM: LDS-staged B (dbuf, 1 barrier/chunk), top-2 fused ----
__device__ __forceinline__ void stage_chunk(
    const u16* __restrict__ ebh, int chbase, char* buf, int t) {
    // 32 codes x 32 ksubs x 16B; lane-linear LDS (p*16)
    #pragma unroll
    for (int i = 0; i < 4; ++i) {
        int p = t + 256 * i;
        int ks = p >> 5, c = p & 31;
        GLOAD_LDS16(ebh + ((size_t)ks * KCODES + chbase + c) * 8, buf + p * 16);
    }
}

__global__ __launch_bounds__(256, 2) void vq_gemm(
    const u16* zah,
    const u16* __restrict__ ebh,
    const float* __restrict__ ee, const float* __restrict__ z2,
    float* out, float* __restrict__ sum, int* __restrict__ count,
    int* __restrict__ list) {
    __shared__ __align__(16) char bs[2][16384];   // double-buffered B chunk
    const int t = threadIdx.x, w = t >> 6, l = t & 63;
    const int lr = l & 15, lg = l >> 4;
    const int rowbase = blockIdx.x * 128;

    // A fragments in registers: [rowfrag][kstep]
    bf16x8 aH[2][8];
    #pragma unroll
    for (int rf = 0; rf < 2; ++rf)
        #pragma unroll
        for (int s = 0; s < 8; ++s) {
            size_t off = ((size_t)(s * 4 + lg) * NROWS + rowbase + w * 32 + rf * 16 + lr) * 8;
            aH[rf][s] = *(const bf16x8*)(zah + off);
        }

    u64 k1[2][4]; float s1[2][4], s2[2][4];
    #pragma unroll
    for (int rf = 0; rf < 2; ++rf)
        #pragma unroll
        for (int r = 0; r < 4; ++r) { k1[rf][r] = ~0ULL; s1[rf][r] = 1e30f; s2[rf][r] = 1e30f; }

    int cur = 0;
    stage_chunk(ebh, 0, bs[0], t);
    for (int ch = 0; ch < 32; ++ch) {
        __syncthreads();                    // drains this chunk's gload_lds
        if (ch + 1 < 32) stage_chunk(ebh, (ch + 1) * 32, bs[cur ^ 1], t);
        const char* buf = bs[cur];
        const int chbase = ch * 32;

        f32x4 acc[2][2];
        #pragma unroll
        for (int rf = 0; rf < 2; ++rf)
            #pragma unroll
            for (int cf = 0; cf < 2; ++cf) acc[rf][cf] = 0.0f;

        #pragma unroll
        for (int s = 0; s < 8; ++s) {
            #pragma unroll
            for (int cf = 0; cf < 2; ++cf) {
                int off = (((s * 4 + lg) * 32 + cf * 16 + lr) * 16);
                bf16x8 bh = *(const bf16x8*)(buf + off);
                #pragma unroll
                for (int rf = 0; rf < 2; ++rf)
                    acc[rf][cf] = __builtin_amdgcn_mfma_f32_16x16x32_bf16(aH[rf][s], bh, acc[rf][cf], 0, 0, 0);
            }
        }
        // chunk epilogue: per-lane running top-2 over its 2 codes
        #pragma unroll
        for (int cf = 0; cf < 2; ++cf) {
            int code = chbase + cf * 16 + lr;
            float e2c = ee[code];
            #pragma unroll
            for (int rf = 0; rf < 2; ++rf)
                #pragma unroll
                for (int r = 0; r < 4; ++r) {
                    float v = e2c - 2.0f * acc[rf][cf][r];
                    u64 k = pack_key(v, (u32)code);
                    if (k < k1[rf][r]) { s2[rf][r] = fminf(s2[rf][r], s1[rf][r]); s1[rf][r] = v; k1[rf][r] = k; }
                    else               { s2[rf][r] = fminf(s2[rf][r], v); }
                }
        }
        cur ^= 1;
    }
    // butterfly across the 16 lanes of each row group (lr bits only)
    #pragma unroll
    for (int off = 1; off < 16; off <<= 1) {
        #pragma unroll
        for (int rf = 0; rf < 2; ++rf)
            #pragma unroll
            for (int r = 0; r < 4; ++r) {
                u64 ok = __shfl_xor(k1[rf][r], off);
                float os1 = __shfl_xor(s1[rf][r], off);
                float os2 = __shfl_xor(s2[rf][r], off);
                bool other = ok < k1[rf][r];
                float worse = other ? s1[rf][r] : os1;
                if (other) { k1[rf][r] = ok; s1[rf][r] = os1; }
                s2[rf][r] = fminf(fminf(s2[rf][r], os2), worse);
            }
    }
    if (lr == 0) {
        float lsum = 0.0f;
        #pragma unroll
        for (int rf = 0; rf < 2; ++rf)
            #pragma unroll
            for (int r = 0; r < 4; ++r) {
                int row = rowbase + w * 32 + rf * 16 + lg * 4 + r;
                int code = (int)(k1[rf][r] & 1023ULL);
                out[(size_t)IDX_OFF + row] = (float)code;
                lsum += z2[row] + s1[rf][r];
                if (s2[rf][r] <= s1[rf][r] + MARGIN) {
                    int slot = atomicAdd(count, 1);
                    if (slot < RCAP) list[slot] = row;
                }
            }
        atomicAdd(sum, lsum);
    }
}

// ---- tier-2 exact np re-scan, BATCHED 16 rows/block (R6 arithmetic) ----
__global__ __launch_bounds__(256) void vq_rescue(
    const float* __restrict__ Z, const float* __restrict__ E,
    const float* __restrict__ ee, const int* __restrict__ count,
    const int* __restrict__ list, float* out) {
    __shared__ float zrow[RBATCH][DDIM];    // 16 KB
    __shared__ float zacc[RBATCH][16];
    __shared__ float z2s[RBATCH];
    __shared__ u64 rmin[RBATCH];
    __shared__ int rowid[RBATCH];
    int n = *count; if (n > RCAP) n = RCAP;
    const int t = threadIdx.x;
    const int base = blockIdx.x * RBATCH;
    if (base >= n) return;
    int nb = n - base; if (nb > RBATCH) nb = RBATCH;

    if (t < RBATCH) {
        rowid[t] = (t < nb) ? list[base + t] : 0;
        rmin[t] = ~0ULL;
    }
    __syncthreads();
    // stage z rows (coalesced float4): 16 rows x 64 float4
    #pragma unroll
    for (int i = 0; i < RBATCH * (DDIM / 4) / 256; ++i) {
        int p = t + 256 * i;
        int r = p >> 6, c4 = p & 63;
        if (r < nb) ((float4*)zrow[r])[c4] =
            ((const float4*)(Z + (size_t)rowid[r] * DDIM))[c4];
    }
    __syncthreads();
    // np pairwise z2 per row
    if (t < RBATCH * 8) {
        int r = t >> 3, j = t & 7;
        const float* zr = zrow[r];
        float a0 = zr[j] * zr[j], a1 = zr[128 + j] * zr[128 + j];
        for (int i = 8; i < 128; i += 8) {
            a0 += zr[i + j] * zr[i + j];
            a1 += zr[128 + i + j] * zr[128 + i + j];
        }
        zacc[r][j] = a0; zacc[r][8 + j] = a1;
    }
    __syncthreads();
    if (t < RBATCH) {
        const float* a = zacc[t];
        float c0 = ((a[0] + a[1]) + (a[2] + a[3])) + ((a[4] + a[5]) + (a[6] + a[7]));
        float c1 = ((a[8] + a[9]) + (a[10] + a[11])) + ((a[12] + a[13]) + (a[14] + a[15]));
        z2s[t] = c0 + c1;
    }
    __syncthreads();

    // dots: thread t owns codes {t,+256,+512,+768} x all RBATCH rows;
    // strict sequential fp32 FMA chain over k ascending per (row,code).
    float acc[4][RBATCH];
    #pragma unroll
    for (int c = 0; c < 4; ++c)
        #pragma unroll
        for (int r = 0; r < RBATCH; ++r) acc[c][r] = 0.0f;

    for (int d4 = 0; d4 < DDIM / 4; ++d4) {
        float4 ev[4];
        #pragma unroll
        for (int c = 0; c < 4; ++c)
            ev[c] = ((const float4*)(E + (size_t)(t + c * 256) * DDIM))[d4];
        #pragma unroll
        for (int r = 0; r < RBATCH; ++r) {
            float4 zv = ((const float4*)zrow[r])[d4];
            #pragma unroll
            for (int c = 0; c < 4; ++c) {
                float a = acc[c][r];
                a = __fmaf_rn(zv.x, ev[c].x, a); a = __fmaf_rn(zv.y, ev[c].y, a);
                a = __fmaf_rn(zv.z, ev[c].z, a); a = __fmaf_rn(zv.w, ev[c].w, a);
                acc[c][r] = a;
            }
        }
    }
    // per-row argmin: np full-magnitude combine + first-min tie-break
    float e2c[4];
    #pragma unroll
    for (int c = 0; c < 4; ++c) e2c[c] = ee[t + c * 256];
    #pragma unroll
    for (int r = 0; r < RBATCH; ++r) {
        float zr2 = z2s[r];
        u64 best = ~0ULL;
        #pragma unroll
        for (int c = 0; c < 4; ++c) {
            float d = (zr2 + e2c[c]) - 2.0f * acc[c][r];
            u64 k = pack_key(d, (u32)(t + c * 256));
            if (k < best) best = k;
        }
        #pragma unroll
        for (int off = 1; off < 64; off <<= 1) {
            u64 o = __shfl_xor(best, off);
            if (o < best) best = o;
        }
        if ((t & 63) == 0) atomicMin(&rmin[r], best);
    }
    __syncthreads();
    if (t < nb) out[(size_t)IDX_OFF + rowid[t]] = (float)(u32)(rmin[t] & 0xFFFFFFFFu);
}

// ---- gather codebook rows into quantized output (overwrites scratch) ----
__global__ __launch_bounds__(256) void vq_qwrite(const float* __restrict__ E, float* out) {
    __shared__ int qidx[32];
    const int t = threadIdx.x;
    const size_t rowbase = (size_t)blockIdx.x * 32;
    if (t < 32) qidx[t] = (int)out[(size_t)IDX_OFF + rowbase + t];
    __syncthreads();
    float4* outq = (float4*)out;
    #pragma unroll
    for (int k = 0; k < 8; ++k) {
        int idx = t + 256 * k;
        int r = idx >> 6, c4 = idx & 63;
        int code = qidx[r];
        outq[rowbase * 64 + idx] = ((const float4*)(E + (size_t)code * DDIM))[c4];
    }
}

__global__ void vq_finalize(const float* __restrict__ sum, float* __restrict__ out) {
    out[LOSS_OFF] = 1.25f * (*sum) / (float)QSIZE;
}

extern "C" void kernel_launch(void* const* d_in, const int* in_sizes, int n_in,
                              void* d_out, int out_size, void* d_ws, size_t ws_size,
                              hipStream_t stream) {
    const float* Z; const float* E;
    if (in_sizes[0] == QSIZE) { Z = (const float*)d_in[0]; E = (const float*)d_in[1]; }
    else                      { Z = (const float*)d_in[1]; E = (const float*)d_in[0]; }
    float* out = (float*)d_out;
    char* ws = (char*)d_ws;

    float* sum  = (float*)ws;                       // @0
    int*   count = (int*)(ws + 4);                  // @4
    float* ee   = (float*)(ws + 1024);              // 4 KB
    float* z2   = (float*)(ws + 8192);              // 256 KB
    u16*   ebh  = (u16*)(ws + 270336);              // 512 KB
    int*   list = (int*)(ws + 270336 + 524288);     // 64 KB  (total ~0.86 MB)

    // bf16 z scratch lives in the q-output region until vq_qwrite
    u16* zah = (u16*)out;

    vq_pack_cb<<<4, 256, 0, stream>>>(E, ebh, ee, sum, count);
    vq_cvt<<<NROWS / 32, 256, 0, stream>>>(Z, zah, z2);
    vq_gemm<<<NROWS / 128, 256, 0, stream>>>(zah, ebh, ee, z2, out, sum, count, list);
    vq_rescue<<<RCAP / RBATCH, 256, 0, stream>>>(Z, E, ee, count, list, out);
    vq_qwrite<<<NROWS / 32, 256, 0, stream>>>(E, out);
    vq_finalize<<<1, 1, 0, stream>>>(sum, out);
}